// Round 1
// baseline (361.351 us; speedup 1.0000x reference)
//
#include <hip/hip_runtime.h>
#include <stdint.h>

typedef __attribute__((ext_vector_type(4))) float f32x4;
typedef __attribute__((ext_vector_type(8))) short bf16x8;

constexpr int S_ = 2048;
constexpr int D_ = 128;
constexpr int QB = 64;    // q rows per block (16 per wave x 4 waves)
constexpr int KB = 32;    // kv rows per tile
// fold 1/sqrt(128) * log2(e) into Q so scores are already in log2 domain
constexpr float QSCALE = 0.08838834764831845f * 1.4426950408889634f;

__device__ __forceinline__ short f2bf(float f) {
  uint32_t u = __float_as_uint(f);
  u += 0x7fffu + ((u >> 16) & 1u);   // round-to-nearest-even
  return (short)(u >> 16);
}

__global__ __launch_bounds__(256, 4) void attn_fwd_v1(
    const float* __restrict__ q, const float* __restrict__ k,
    const float* __restrict__ v, float* __restrict__ out)
{
  // K tile: [32][128] bf16, XOR-swizzled granules (16B) to avoid 32-way conflicts
  __shared__ __align__(16) short Klds[KB * D_];
  // V tile transposed: [d=128][kv=32 padded to 40] bf16 -> PV B-frag is 16B contiguous
  __shared__ __align__(16) short Vlds[D_ * 40];
  // per-wave P buffer [16 rows][32 cols padded to 40]
  __shared__ __align__(16) short Plds[4][16 * 40];

  // bijective XCD swizzle: XCD i gets a contiguous chunk => 4 (b,h) values/XCD,
  // their K/V stream through that XCD's L2
  const int lid = blockIdx.x;
  const int swz = (lid & 7) * 128 + (lid >> 3);
  const int qt = swz & 31;        // q tile index
  const int bh = swz >> 5;        // (b,h) flat index

  const int tid = threadIdx.x;
  const int wid = tid >> 6;
  const int lane = tid & 63;
  const int l16 = lane & 15;
  const int lhi = lane >> 4;

  const int qrow0 = qt * QB + wid * 16;

  const float* qg = q + ((size_t)bh * S_ + qrow0 + l16) * D_;
  const float* kg = k + (size_t)bh * S_ * D_;
  const float* vg = v + (size_t)bh * S_ * D_;

  // Q fragments: lane holds Q[qrow0 + l16][ks*32 + lhi*8 + j], pre-scaled
  bf16x8 aq[4];
#pragma unroll
  for (int ks = 0; ks < 4; ++ks) {
    const float* p = qg + ks * 32 + lhi * 8;
    float4 f0 = *reinterpret_cast<const float4*>(p);
    float4 f1 = *reinterpret_cast<const float4*>(p + 4);
    bf16x8 a;
    a[0] = f2bf(f0.x * QSCALE); a[1] = f2bf(f0.y * QSCALE);
    a[2] = f2bf(f0.z * QSCALE); a[3] = f2bf(f0.w * QSCALE);
    a[4] = f2bf(f1.x * QSCALE); a[5] = f2bf(f1.y * QSCALE);
    a[6] = f2bf(f1.z * QSCALE); a[7] = f2bf(f1.w * QSCALE);
    aq[ks] = a;
  }

  float mrow[4], lrow[4];
  f32x4 oacc[8];
#pragma unroll
  for (int r = 0; r < 4; ++r) { mrow[r] = -1e30f; lrow[r] = 0.f; }
#pragma unroll
  for (int i = 0; i < 8; ++i) oacc[i] = (f32x4){0.f, 0.f, 0.f, 0.f};

  for (int t = 0; t < S_ / KB; ++t) {
    const int kv0 = t * KB;
    __syncthreads();   // previous tile's compute done before overwrite

    // ---- stage K (vector writes, swizzled) and V (transposed scalar writes) ----
#pragma unroll
    for (int i = 0; i < 2; ++i) {
      const int g = tid * 2 + i;           // granule id: 512 granules of 8 elems
      const int row = g >> 4;
      const int c8 = g & 15;
      const float* ksrc = kg + (size_t)(kv0 + row) * D_ + c8 * 8;
      float4 f0 = *reinterpret_cast<const float4*>(ksrc);
      float4 f1 = *reinterpret_cast<const float4*>(ksrc + 4);
      bf16x8 kk;
      kk[0] = f2bf(f0.x); kk[1] = f2bf(f0.y); kk[2] = f2bf(f0.z); kk[3] = f2bf(f0.w);
      kk[4] = f2bf(f1.x); kk[5] = f2bf(f1.y); kk[6] = f2bf(f1.z); kk[7] = f2bf(f1.w);
      *reinterpret_cast<bf16x8*>(
          &Klds[row * D_ + ((c8 * 8) ^ ((row & 7) << 3))]) = kk;

      const float* vsrc = vg + (size_t)(kv0 + row) * D_ + c8 * 8;
      float4 g0 = *reinterpret_cast<const float4*>(vsrc);
      float4 g1 = *reinterpret_cast<const float4*>(vsrc + 4);
      const int dbase = c8 * 8;
      Vlds[(dbase + 0) * 40 + row] = f2bf(g0.x);
      Vlds[(dbase + 1) * 40 + row] = f2bf(g0.y);
      Vlds[(dbase + 2) * 40 + row] = f2bf(g0.z);
      Vlds[(dbase + 3) * 40 + row] = f2bf(g0.w);
      Vlds[(dbase + 4) * 40 + row] = f2bf(g1.x);
      Vlds[(dbase + 5) * 40 + row] = f2bf(g1.y);
      Vlds[(dbase + 6) * 40 + row] = f2bf(g1.z);
      Vlds[(dbase + 7) * 40 + row] = f2bf(g1.w);
    }
    __syncthreads();

    // ---- QK^T: S(16x32) in log2 domain ----
    f32x4 sfrag[2];
#pragma unroll
    for (int kb = 0; kb < 2; ++kb) {
      f32x4 acc = (f32x4){0.f, 0.f, 0.f, 0.f};
#pragma unroll
      for (int ks = 0; ks < 4; ++ks) {
        const int rowk = kb * 16 + l16;
        bf16x8 bk = *reinterpret_cast<const bf16x8*>(
            &Klds[rowk * D_ + (((ks * 4 + lhi) * 8) ^ ((rowk & 7) << 3))]);
        acc = __builtin_amdgcn_mfma_f32_16x16x32_bf16(aq[ks], bk, acc, 0, 0, 0);
      }
      sfrag[kb] = acc;
    }

    // ---- online softmax (wave-parallel; rows live in reg r, replicated over 16 lanes) ----
    float mt[4];
#pragma unroll
    for (int r = 0; r < 4; ++r) mt[r] = fmaxf(sfrag[0][r], sfrag[1][r]);
#pragma unroll
    for (int off = 1; off < 16; off <<= 1)
#pragma unroll
      for (int r = 0; r < 4; ++r) mt[r] = fmaxf(mt[r], __shfl_xor(mt[r], off, 64));

    float al[4], ps[4];
#pragma unroll
    for (int r = 0; r < 4; ++r) {
      float mn = fmaxf(mrow[r], mt[r]);
      al[r] = exp2f(mrow[r] - mn);
      mrow[r] = mn;
      ps[r] = 0.f;
    }
#pragma unroll
    for (int kb = 0; kb < 2; ++kb)
#pragma unroll
      for (int r = 0; r < 4; ++r) {
        float p = exp2f(sfrag[kb][r] - mrow[r]);
        ps[r] += p;
        Plds[wid][(lhi * 4 + r) * 40 + kb * 16 + l16] = f2bf(p);
      }
#pragma unroll
    for (int off = 1; off < 16; off <<= 1)
#pragma unroll
      for (int r = 0; r < 4; ++r) ps[r] += __shfl_xor(ps[r], off, 64);
#pragma unroll
    for (int r = 0; r < 4; ++r) lrow[r] = lrow[r] * al[r] + ps[r];
#pragma unroll
    for (int i = 0; i < 8; ++i)
#pragma unroll
      for (int r = 0; r < 4; ++r) oacc[i][r] *= al[r];

    // ---- PV: O(16x128) += P(16x32) * V(32x128) ----
    bf16x8 ap = *reinterpret_cast<const bf16x8*>(&Plds[wid][l16 * 40 + lhi * 8]);
#pragma unroll
    for (int d0 = 0; d0 < 8; ++d0) {
      bf16x8 bv = *reinterpret_cast<const bf16x8*>(
          &Vlds[(d0 * 16 + l16) * 40 + lhi * 8]);
      oacc[d0] = __builtin_amdgcn_mfma_f32_16x16x32_bf16(ap, bv, oacc[d0], 0, 0, 0);
    }
  }

  // ---- epilogue: normalize and store fp32 ----
#pragma unroll
  for (int r = 0; r < 4; ++r) {
    float inv = 1.0f / lrow[r];
    float* orow = out + ((size_t)bh * S_ + qrow0 + lhi * 4 + r) * D_ + l16;
#pragma unroll
    for (int d0 = 0; d0 < 8; ++d0) orow[d0 * 16] = oacc[d0][r] * inv;
  }
}

extern "C" void kernel_launch(void* const* d_in, const int* in_sizes, int n_in,
                              void* d_out, int out_size, void* d_ws, size_t ws_size,
                              hipStream_t stream) {
  (void)in_sizes; (void)n_in; (void)d_ws; (void)ws_size; (void)out_size;
  const float* q = (const float*)d_in[0];
  const float* k = (const float*)d_in[1];
  const float* v = (const float*)d_in[2];
  float* o = (float*)d_out;
  dim3 grid(1024, 1, 1), block(256, 1, 1);
  hipLaunchKernelGGL(attn_fwd_v1, grid, block, 0, stream, q, k, v, o);
}

// Round 2
// 152.871 us; speedup vs baseline: 2.3638x; 2.3638x over previous
//
#include <hip/hip_runtime.h>
#include <stdint.h>

typedef __attribute__((ext_vector_type(4))) float f32x4;
typedef __attribute__((ext_vector_type(8))) short bf16x8;
typedef __attribute__((ext_vector_type(4))) short bf16x4;

constexpr int S_ = 2048;
constexpr int D_ = 128;
constexpr int BH = 32;
// fold 1/sqrt(128) * log2(e) into Q so scores are in log2 domain
constexpr float QSCALE = 0.08838834764831845f * 1.4426950408889634f;

__device__ __forceinline__ short f2bf(float f) {
  uint32_t u = __float_as_uint(f);
  u += 0x7fffu + ((u >> 16) & 1u);   // round-to-nearest-even
  return (short)(u >> 16);
}

// ================= prep 1: q,k -> bf16 (q pre-scaled) =================
__global__ void prep_qk(const float* __restrict__ q, const float* __restrict__ k,
                        short* __restrict__ qb, short* __restrict__ kb) {
  const size_t N8 = (size_t)BH * S_ * D_ / 8;
  size_t i = (size_t)blockIdx.x * blockDim.x + threadIdx.x;
  const size_t stride = (size_t)gridDim.x * blockDim.x;
  for (; i < N8; i += stride) {
    float4 a = reinterpret_cast<const float4*>(q)[i * 2];
    float4 b = reinterpret_cast<const float4*>(q)[i * 2 + 1];
    bf16x8 o;
    o[0] = f2bf(a.x * QSCALE); o[1] = f2bf(a.y * QSCALE);
    o[2] = f2bf(a.z * QSCALE); o[3] = f2bf(a.w * QSCALE);
    o[4] = f2bf(b.x * QSCALE); o[5] = f2bf(b.y * QSCALE);
    o[6] = f2bf(b.z * QSCALE); o[7] = f2bf(b.w * QSCALE);
    reinterpret_cast<bf16x8*>(qb)[i] = o;
    a = reinterpret_cast<const float4*>(k)[i * 2];
    b = reinterpret_cast<const float4*>(k)[i * 2 + 1];
    o[0] = f2bf(a.x); o[1] = f2bf(a.y); o[2] = f2bf(a.z); o[3] = f2bf(a.w);
    o[4] = f2bf(b.x); o[5] = f2bf(b.y); o[6] = f2bf(b.z); o[7] = f2bf(b.w);
    reinterpret_cast<bf16x8*>(kb)[i] = o;
  }
}

// ================= prep 2: v -> bf16 transposed per head: vt[bh][d][s] =================
__global__ void prep_vt(const float* __restrict__ v, short* __restrict__ vt) {
  __shared__ __align__(16) short Lt[64][136];   // 136*2=272B row stride, 16B aligned
  const int bh = blockIdx.x >> 5;
  const int s0 = (blockIdx.x & 31) * 64;
  const int t = threadIdx.x;
#pragma unroll
  for (int i = 0; i < 4; ++i) {
    int g = t + 256 * i;             // 1024 granules of 8 elems (64 rows x 16)
    int r = g >> 4, c8 = g & 15;
    const float* src = v + ((size_t)bh * S_ + s0 + r) * D_ + c8 * 8;
    float4 f0 = *reinterpret_cast<const float4*>(src);
    float4 f1 = *reinterpret_cast<const float4*>(src + 4);
    bf16x8 o;
    o[0] = f2bf(f0.x); o[1] = f2bf(f0.y); o[2] = f2bf(f0.z); o[3] = f2bf(f0.w);
    o[4] = f2bf(f1.x); o[5] = f2bf(f1.y); o[6] = f2bf(f1.z); o[7] = f2bf(f1.w);
    *reinterpret_cast<bf16x8*>(&Lt[r][c8 * 8]) = o;
  }
  __syncthreads();
#pragma unroll
  for (int i = 0; i < 4; ++i) {
    int g = t * 4 + i;               // d = t>>1 per thread-pair, spreads LDS banks
    int d = g >> 3, s8 = g & 7;
    bf16x8 o;
#pragma unroll
    for (int j = 0; j < 8; ++j) o[j] = Lt[s8 * 8 + j][d];
    *reinterpret_cast<bf16x8*>(&vt[((size_t)bh * D_ + d) * S_ + s0 + s8 * 8]) = o;
  }
}

// ================= main attention: 8 waves, 16 q-rows/wave, KB=64 =================
// Swapped QK^T (S^T = K * Q^T) and transposed PV (O^T = Vt * P^T): all LDS ops vectorized.
__global__ __launch_bounds__(512, 4) void attn_fwd_v2(
    const short* __restrict__ qb, const short* __restrict__ kb,
    const short* __restrict__ vt, float* __restrict__ out)
{
  __shared__ __align__(16) short Klds[64 * 128];     // granule-XOR swizzled
  __shared__ __align__(16) short Vlds[128 * 72];     // [d][kv] pad 72
  __shared__ __align__(16) short Plds[8][16 * 72];   // per-wave P [q16][kv64+pad]

  const int lid = blockIdx.x;
  const int swz = (lid & 7) * 64 + (lid >> 3);   // bijective: 512 % 8 == 0
  const int qt = swz & 15;
  const int bh = swz >> 4;

  const int tid = threadIdx.x;
  const int wid = tid >> 6;
  const int lane = tid & 63;
  const int l16 = lane & 15;
  const int lhi = lane >> 4;

  const int qrow0 = qt * 128 + wid * 16;

  // Q fragments (bf16, pre-scaled): B-frag role: Q[qrow0+l16][ks*32+lhi*8+j]
  const short* qg = qb + ((size_t)bh * S_ + qrow0 + l16) * D_;
  bf16x8 aq[4];
#pragma unroll
  for (int ks = 0; ks < 4; ++ks)
    aq[ks] = *reinterpret_cast<const bf16x8*>(qg + ks * 32 + lhi * 8);

  float m = -1e30f, l = 0.f;
  f32x4 oacc[8];
#pragma unroll
  for (int i = 0; i < 8; ++i) oacc[i] = (f32x4){0.f, 0.f, 0.f, 0.f};

  const short* kg = kb + (size_t)bh * S_ * D_;
  const short* vg = vt + (size_t)bh * D_ * S_;   // [d][s]
  short* Pw = &Plds[wid][0];

  for (int t = 0; t < S_ / 64; ++t) {
    const int kv0 = t * 64;
    __syncthreads();
    // ---- stage K[64][128] (swizzled) and V[d 128][kv 64] (pure 16B copies) ----
#pragma unroll
    for (int i = 0; i < 2; ++i) {
      int g = tid + 512 * i;
      int row = g >> 4, c8 = g & 15;
      bf16x8 kk = *reinterpret_cast<const bf16x8*>(
          kg + (size_t)(kv0 + row) * D_ + c8 * 8);
      *reinterpret_cast<bf16x8*>(&Klds[row * 128 + (c8 ^ (row & 7)) * 8]) = kk;
      int d = g >> 3, kv8 = g & 7;
      bf16x8 vv = *reinterpret_cast<const bf16x8*>(
          vg + (size_t)d * S_ + kv0 + kv8 * 8);
      *reinterpret_cast<bf16x8*>(&Vlds[d * 72 + kv8 * 8]) = vv;
    }
    __syncthreads();

    // ---- QK^T: S^T[kv16][q16] per kb; lane holds S[q=l16][kv=kb*16+lhi*4+r] ----
    f32x4 sf[4];
#pragma unroll
    for (int kbb = 0; kbb < 4; ++kbb) {
      f32x4 acc = (f32x4){0.f, 0.f, 0.f, 0.f};
#pragma unroll
      for (int ks = 0; ks < 4; ++ks) {
        const int rowk = kbb * 16 + l16;
        bf16x8 ak = *reinterpret_cast<const bf16x8*>(
            &Klds[rowk * 128 + (((ks * 4 + lhi) ^ (rowk & 7)) * 8)]);
        acc = __builtin_amdgcn_mfma_f32_16x16x32_bf16(ak, aq[ks], acc, 0, 0, 0);
      }
      sf[kbb] = acc;
    }

    // ---- online softmax: lane owns q=l16 (16 kv values), reduce across lhi ----
    float pmax = fmaxf(fmaxf(fmaxf(sf[0][0], sf[0][1]), fmaxf(sf[0][2], sf[0][3])),
                       fmaxf(fmaxf(sf[1][0], sf[1][1]), fmaxf(sf[1][2], sf[1][3])));
    pmax = fmaxf(pmax, fmaxf(fmaxf(fmaxf(sf[2][0], sf[2][1]), fmaxf(sf[2][2], sf[2][3])),
                             fmaxf(fmaxf(sf[3][0], sf[3][1]), fmaxf(sf[3][2], sf[3][3]))));
    pmax = fmaxf(pmax, __shfl_xor(pmax, 16, 64));
    pmax = fmaxf(pmax, __shfl_xor(pmax, 32, 64));
    const float mn = fmaxf(m, pmax);
    const float al = exp2f(m - mn);
    m = mn;
    float ps = 0.f;
#pragma unroll
    for (int kbb = 0; kbb < 4; ++kbb) {
      bf16x4 pw;
#pragma unroll
      for (int r = 0; r < 4; ++r) {
        float p = exp2f(sf[kbb][r] - mn);
        ps += p;
        pw[r] = f2bf(p);
      }
      // S^T c-frag rows are 4 consecutive kv for fixed q -> aligned b64 write
      *reinterpret_cast<bf16x4*>(&Pw[l16 * 72 + kbb * 16 + lhi * 4]) = pw;
    }
    ps += __shfl_xor(ps, 16, 64);
    ps += __shfl_xor(ps, 32, 64);
    l = l * al + ps;
#pragma unroll
    for (int d0 = 0; d0 < 8; ++d0)
#pragma unroll
      for (int r = 0; r < 4; ++r) oacc[d0][r] *= al;

    // ---- PV: O^T[d][q] += Vt[d][kv] * P^T[kv][q]; all reads contiguous 16B ----
#pragma unroll
    for (int kc = 0; kc < 2; ++kc) {
      bf16x8 pb = *reinterpret_cast<const bf16x8*>(
          &Pw[l16 * 72 + kc * 32 + lhi * 8]);
#pragma unroll
      for (int d0 = 0; d0 < 8; ++d0) {
        bf16x8 av = *reinterpret_cast<const bf16x8*>(
            &Vlds[(d0 * 16 + l16) * 72 + kc * 32 + lhi * 8]);
        oacc[d0] = __builtin_amdgcn_mfma_f32_16x16x32_bf16(av, pb, oacc[d0], 0, 0, 0);
      }
    }
  }

  // ---- epilogue: O^T frag -> out[q][d], float4 stores ----
  const float inv = 1.0f / l;
#pragma unroll
  for (int d0 = 0; d0 < 8; ++d0) {
    float4 o4 = {oacc[d0][0] * inv, oacc[d0][1] * inv,
                 oacc[d0][2] * inv, oacc[d0][3] * inv};
    *reinterpret_cast<float4*>(
        out + ((size_t)bh * S_ + qrow0 + l16) * D_ + d0 * 16 + lhi * 4) = o4;
  }
}

// ================= fallback (R1 kernel) if ws is too small =================
__global__ __launch_bounds__(256, 4) void attn_fwd_v1(
    const float* __restrict__ q, const float* __restrict__ k,
    const float* __restrict__ v, float* __restrict__ out)
{
  __shared__ __align__(16) short Klds[32 * 128];
  __shared__ __align__(16) short Vlds[128 * 40];
  __shared__ __align__(16) short Plds[4][16 * 40];
  const int lid = blockIdx.x;
  const int swz = (lid & 7) * 128 + (lid >> 3);
  const int qt = swz & 31;
  const int bh = swz >> 5;
  const int tid = threadIdx.x;
  const int wid = tid >> 6;
  const int lane = tid & 63;
  const int l16 = lane & 15;
  const int lhi = lane >> 4;
  const int qrow0 = qt * 64 + wid * 16;
  const float* qg = q + ((size_t)bh * S_ + qrow0 + l16) * D_;
  const float* kg = k + (size_t)bh * S_ * D_;
  const float* vg = v + (size_t)bh * S_ * D_;
  bf16x8 aq[4];
#pragma unroll
  for (int ks = 0; ks < 4; ++ks) {
    const float* p = qg + ks * 32 + lhi * 8;
    float4 f0 = *reinterpret_cast<const float4*>(p);
    float4 f1 = *reinterpret_cast<const float4*>(p + 4);
    bf16x8 a;
    a[0] = f2bf(f0.x * QSCALE); a[1] = f2bf(f0.y * QSCALE);
    a[2] = f2bf(f0.z * QSCALE); a[3] = f2bf(f0.w * QSCALE);
    a[4] = f2bf(f1.x * QSCALE); a[5] = f2bf(f1.y * QSCALE);
    a[6] = f2bf(f1.z * QSCALE); a[7] = f2bf(f1.w * QSCALE);
    aq[ks] = a;
  }
  float mrow[4], lrow[4];
  f32x4 oacc[8];
#pragma unroll
  for (int r = 0; r < 4; ++r) { mrow[r] = -1e30f; lrow[r] = 0.f; }
#pragma unroll
  for (int i = 0; i < 8; ++i) oacc[i] = (f32x4){0.f, 0.f, 0.f, 0.f};
  for (int t = 0; t < S_ / 32; ++t) {
    const int kv0 = t * 32;
    __syncthreads();
#pragma unroll
    for (int i = 0; i < 2; ++i) {
      const int g = tid * 2 + i;
      const int row = g >> 4;
      const int c8 = g & 15;
      const float* ksrc = kg + (size_t)(kv0 + row) * D_ + c8 * 8;
      float4 f0 = *reinterpret_cast<const float4*>(ksrc);
      float4 f1 = *reinterpret_cast<const float4*>(ksrc + 4);
      bf16x8 kk;
      kk[0] = f2bf(f0.x); kk[1] = f2bf(f0.y); kk[2] = f2bf(f0.z); kk[3] = f2bf(f0.w);
      kk[4] = f2bf(f1.x); kk[5] = f2bf(f1.y); kk[6] = f2bf(f1.z); kk[7] = f2bf(f1.w);
      *reinterpret_cast<bf16x8*>(
          &Klds[row * D_ + ((c8 * 8) ^ ((row & 7) << 3))]) = kk;
      const float* vsrc = vg + (size_t)(kv0 + row) * D_ + c8 * 8;
      float4 g0 = *reinterpret_cast<const float4*>(vsrc);
      float4 g1 = *reinterpret_cast<const float4*>(vsrc + 4);
      const int dbase = c8 * 8;
      Vlds[(dbase + 0) * 40 + row] = f2bf(g0.x);
      Vlds[(dbase + 1) * 40 + row] = f2bf(g0.y);
      Vlds[(dbase + 2) * 40 + row] = f2bf(g0.z);
      Vlds[(dbase + 3) * 40 + row] = f2bf(g0.w);
      Vlds[(dbase + 4) * 40 + row] = f2bf(g1.x);
      Vlds[(dbase + 5) * 40 + row] = f2bf(g1.y);
      Vlds[(dbase + 6) * 40 + row] = f2bf(g1.z);
      Vlds[(dbase + 7) * 40 + row] = f2bf(g1.w);
    }
    __syncthreads();
    f32x4 sfrag[2];
#pragma unroll
    for (int kb = 0; kb < 2; ++kb) {
      f32x4 acc = (f32x4){0.f, 0.f, 0.f, 0.f};
#pragma unroll
      for (int ks = 0; ks < 4; ++ks) {
        const int rowk = kb * 16 + l16;
        bf16x8 bk = *reinterpret_cast<const bf16x8*>(
            &Klds[rowk * D_ + (((ks * 4 + lhi) * 8) ^ ((rowk & 7) << 3))]);
        acc = __builtin_amdgcn_mfma_f32_16x16x32_bf16(aq[ks], bk, acc, 0, 0, 0);
      }
      sfrag[kb] = acc;
    }
    float mt[4];
#pragma unroll
    for (int r = 0; r < 4; ++r) mt[r] = fmaxf(sfrag[0][r], sfrag[1][r]);
#pragma unroll
    for (int off = 1; off < 16; off <<= 1)
#pragma unroll
      for (int r = 0; r < 4; ++r) mt[r] = fmaxf(mt[r], __shfl_xor(mt[r], off, 64));
    float al[4], ps[4];
#pragma unroll
    for (int r = 0; r < 4; ++r) {
      float mn = fmaxf(mrow[r], mt[r]);
      al[r] = exp2f(mrow[r] - mn);
      mrow[r] = mn;
      ps[r] = 0.f;
    }
#pragma unroll
    for (int kb = 0; kb < 2; ++kb)
#pragma unroll
      for (int r = 0; r < 4; ++r) {
        float p = exp2f(sfrag[kb][r] - mrow[r]);
        ps[r] += p;
        Plds[wid][(lhi * 4 + r) * 40 + kb * 16 + l16] = f2bf(p);
      }
#pragma unroll
    for (int off = 1; off < 16; off <<= 1)
#pragma unroll
      for (int r = 0; r < 4; ++r) ps[r] += __shfl_xor(ps[r], off, 64);
#pragma unroll
    for (int r = 0; r < 4; ++r) lrow[r] = lrow[r] * al[r] + ps[r];
#pragma unroll
    for (int i = 0; i < 8; ++i)
#pragma unroll
      for (int r = 0; r < 4; ++r) oacc[i][r] *= al[r];
    bf16x8 ap = *reinterpret_cast<const bf16x8*>(&Plds[wid][l16 * 40 + lhi * 8]);
#pragma unroll
    for (int d0 = 0; d0 < 8; ++d0) {
      bf16x8 bv = *reinterpret_cast<const bf16x8*>(
          &Vlds[(d0 * 16 + l16) * 40 + lhi * 8]);
      oacc[d0] = __builtin_amdgcn_mfma_f32_16x16x32_bf16(ap, bv, oacc[d0], 0, 0, 0);
    }
  }
#pragma unroll
  for (int r = 0; r < 4; ++r) {
    float inv = 1.0f / lrow[r];
    float* orow = out + ((size_t)bh * S_ + qrow0 + lhi * 4 + r) * D_ + l16;
#pragma unroll
    for (int d0 = 0; d0 < 8; ++d0) orow[d0 * 16] = oacc[d0][r] * inv;
  }
}

extern "C" void kernel_launch(void* const* d_in, const int* in_sizes, int n_in,
                              void* d_out, int out_size, void* d_ws, size_t ws_size,
                              hipStream_t stream) {
  (void)in_sizes; (void)n_in; (void)out_size;
  const float* q = (const float*)d_in[0];
  const float* k = (const float*)d_in[1];
  const float* v = (const float*)d_in[2];
  float* o = (float*)d_out;
  const size_t NEL = (size_t)BH * S_ * D_;            // 8388608
  const size_t need = NEL * 3 * sizeof(short);        // 50.3 MB
  if (ws_size >= need) {
    short* qb = (short*)d_ws;
    short* kb = qb + NEL;
    short* vt = kb + NEL;
    hipLaunchKernelGGL(prep_qk, dim3(2048), dim3(256), 0, stream, q, k, qb, kb);
    hipLaunchKernelGGL(prep_vt, dim3(1024), dim3(256), 0, stream, v, vt);
    hipLaunchKernelGGL(attn_fwd_v2, dim3(512), dim3(512), 0, stream, qb, kb, vt, o);
  } else {
    hipLaunchKernelGGL(attn_fwd_v1, dim3(1024), dim3(256), 0, stream, q, k, v, o);
  }
}

// Round 3
// 128.181 us; speedup vs baseline: 2.8191x; 1.1926x over previous
//
#include <hip/hip_runtime.h>
#include <stdint.h>

typedef __attribute__((ext_vector_type(4))) float f32x4;
typedef __attribute__((ext_vector_type(8))) short bf16x8;
typedef __attribute__((ext_vector_type(4))) short bf16x4;

constexpr int S_ = 2048;
constexpr int D_ = 128;
constexpr int BH = 32;
constexpr int KB = 64;
constexpr int NT = S_ / KB;
// fold 1/sqrt(128) * log2(e) into Q so scores are in log2 domain
constexpr float QSCALE = 0.08838834764831845f * 1.4426950408889634f;

__device__ __forceinline__ short f2bf(float f) {       // RNE (prep / Q)
  uint32_t u = __float_as_uint(f);
  u += 0x7fffu + ((u >> 16) & 1u);
  return (short)(u >> 16);
}
__device__ __forceinline__ short f2bf_fast(float f) {  // ties-away, 2 ops (P only)
  return (short)((__float_as_uint(f) + 0x8000u) >> 16);
}

__device__ __forceinline__ void gll16(const void* g, void* l) {
  __builtin_amdgcn_global_load_lds(
      (const __attribute__((address_space(1))) void*)g,
      (__attribute__((address_space(3))) void*)l, 16, 0, 0);
}

// ================= prep 1: k -> bf16 =================
__global__ void prep_k(const float* __restrict__ k, short* __restrict__ kb) {
  const size_t N8 = (size_t)BH * S_ * D_ / 8;
  size_t i = (size_t)blockIdx.x * blockDim.x + threadIdx.x;
  const size_t stride = (size_t)gridDim.x * blockDim.x;
  for (; i < N8; i += stride) {
    float4 a = reinterpret_cast<const float4*>(k)[i * 2];
    float4 b = reinterpret_cast<const float4*>(k)[i * 2 + 1];
    bf16x8 o;
    o[0] = f2bf(a.x); o[1] = f2bf(a.y); o[2] = f2bf(a.z); o[3] = f2bf(a.w);
    o[4] = f2bf(b.x); o[5] = f2bf(b.y); o[6] = f2bf(b.z); o[7] = f2bf(b.w);
    reinterpret_cast<bf16x8*>(kb)[i] = o;
  }
}

// ================= prep 2: v -> bf16 transposed per head: vt[bh][d][s] =================
__global__ void prep_vt(const float* __restrict__ v, short* __restrict__ vt) {
  __shared__ __align__(16) short Lt[64][136];
  const int bh = blockIdx.x >> 5;
  const int s0 = (blockIdx.x & 31) * 64;
  const int t = threadIdx.x;
#pragma unroll
  for (int i = 0; i < 4; ++i) {
    int g = t + 256 * i;
    int r = g >> 4, c8 = g & 15;
    const float* src = v + ((size_t)bh * S_ + s0 + r) * D_ + c8 * 8;
    float4 f0 = *reinterpret_cast<const float4*>(src);
    float4 f1 = *reinterpret_cast<const float4*>(src + 4);
    bf16x8 o;
    o[0] = f2bf(f0.x); o[1] = f2bf(f0.y); o[2] = f2bf(f0.z); o[3] = f2bf(f0.w);
    o[4] = f2bf(f1.x); o[5] = f2bf(f1.y); o[6] = f2bf(f1.z); o[7] = f2bf(f1.w);
    *reinterpret_cast<bf16x8*>(&Lt[r][c8 * 8]) = o;
  }
  __syncthreads();
#pragma unroll
  for (int i = 0; i < 4; ++i) {
    int g = t * 4 + i;
    int d = g >> 3, s8 = g & 7;
    bf16x8 o;
#pragma unroll
    for (int j = 0; j < 8; ++j) o[j] = Lt[s8 * 8 + j][d];
    *reinterpret_cast<bf16x8*>(&vt[((size_t)bh * D_ + d) * S_ + s0 + s8 * 8]) = o;
  }
}

// ============ main attention: 4 waves x 32 q-rows, KB=64, dbuf gll staging ============
__global__ __launch_bounds__(256, 2) void attn_fwd_v3(
    const float* __restrict__ q, const short* __restrict__ kbf,
    const short* __restrict__ vt, float* __restrict__ out)
{
  __shared__ __align__(16) short Klds[2][64 * 128];   // [row][col], granule-XOR swizzle
  __shared__ __align__(16) short Vlds[2][128 * 64];   // [d][kv], granule-XOR swizzle
  __shared__ __align__(16) short Plds[4][32 * 64];    // per-wave [q][kv], granule-XOR swizzle

  const int lid = blockIdx.x;
  const int swz = (lid & 7) * 64 + (lid >> 3);   // bijective: 512 % 8 == 0
  const int qt = swz & 15;
  const int bh = swz >> 4;

  const int tid = threadIdx.x;
  const int wid = tid >> 6;
  const int lane = tid & 63;
  const int l16 = lane & 15;
  const int lhi = lane >> 4;

  const int qrow0 = qt * 128 + wid * 32;

  // ---- Q fragments from fp32 global (read exactly once -> no prep), scaled ----
  bf16x8 aq[2][4];
#pragma unroll
  for (int qs = 0; qs < 2; ++qs)
#pragma unroll
    for (int ks = 0; ks < 4; ++ks) {
      const float* p = q + ((size_t)bh * S_ + qrow0 + qs * 16 + l16) * D_ + ks * 32 + lhi * 8;
      float4 f0 = *reinterpret_cast<const float4*>(p);
      float4 f1 = *reinterpret_cast<const float4*>(p + 4);
      bf16x8 a;
      a[0] = f2bf(f0.x * QSCALE); a[1] = f2bf(f0.y * QSCALE);
      a[2] = f2bf(f0.z * QSCALE); a[3] = f2bf(f0.w * QSCALE);
      a[4] = f2bf(f1.x * QSCALE); a[5] = f2bf(f1.y * QSCALE);
      a[6] = f2bf(f1.z * QSCALE); a[7] = f2bf(f1.w * QSCALE);
      aq[qs][ks] = a;
    }

  const short* kg = kbf + (size_t)bh * S_ * D_;
  const short* vg = vt + (size_t)bh * D_ * S_;

  // ---- per-lane pre-swizzled staging source offsets (gll: linear LDS dest) ----
  int koff[4], voff[4];
#pragma unroll
  for (int j = 0; j < 4; ++j) {
    const int krow = wid * 16 + j * 4 + lhi;          // LDS granule G=wid*256+j*64+lane
    koff[j] = krow * D_ + ((l16 ^ (krow & 7)) * 8);
    const int vd = wid * 32 + j * 8 + (lane >> 3);
    voff[j] = vd * S_ + (((lane & 7) ^ (vd & 7)) * 8);
  }

  auto stage = [&](int buf, int kv0) {
    const short* ksrc = kg + (size_t)kv0 * D_;
    const short* vsrc = vg + kv0;
#pragma unroll
    for (int j = 0; j < 4; ++j)
      gll16(ksrc + koff[j], &Klds[buf][wid * 2048 + j * 512]);
#pragma unroll
    for (int j = 0; j < 4; ++j)
      gll16(vsrc + voff[j], &Vlds[buf][wid * 2048 + j * 512]);
  };

  float m[2] = {-1e30f, -1e30f}, l[2] = {0.f, 0.f};
  f32x4 oacc[2][8];
#pragma unroll
  for (int qs = 0; qs < 2; ++qs)
#pragma unroll
    for (int i = 0; i < 8; ++i) oacc[qs][i] = (f32x4){0.f, 0.f, 0.f, 0.f};

  short* Pw = &Plds[wid][0];

  stage(0, 0);
  int cur = 0;
  for (int t = 0; t < NT; ++t) {
    __syncthreads();            // drains this wave's gll (tile t) + joins waves
    if (t + 1 < NT) stage(cur ^ 1, (t + 1) * KB);

    // ---- QK^T: S^T = K * Q^T; K-frag reused across both q-subtiles ----
    f32x4 sf[2][4];
#pragma unroll
    for (int qs = 0; qs < 2; ++qs)
#pragma unroll
      for (int kbb = 0; kbb < 4; ++kbb) sf[qs][kbb] = (f32x4){0.f, 0.f, 0.f, 0.f};
    __builtin_amdgcn_s_setprio(1);
#pragma unroll
    for (int kbb = 0; kbb < 4; ++kbb) {
      const int rowk = kbb * 16 + l16;
#pragma unroll
      for (int ks = 0; ks < 4; ++ks) {
        bf16x8 ak = *reinterpret_cast<const bf16x8*>(
            &Klds[cur][rowk * D_ + (((ks * 4 + lhi) ^ (rowk & 7)) * 8)]);
        sf[0][kbb] = __builtin_amdgcn_mfma_f32_16x16x32_bf16(ak, aq[0][ks], sf[0][kbb], 0, 0, 0);
        sf[1][kbb] = __builtin_amdgcn_mfma_f32_16x16x32_bf16(ak, aq[1][ks], sf[1][kbb], 0, 0, 0);
      }
    }
    __builtin_amdgcn_s_setprio(0);

    // ---- online softmax (defer-max THR=8 in log2 domain) ----
#pragma unroll
    for (int qs = 0; qs < 2; ++qs) {
      float pm = fmaxf(fmaxf(fmaxf(sf[qs][0][0], sf[qs][0][1]), fmaxf(sf[qs][0][2], sf[qs][0][3])),
                       fmaxf(fmaxf(sf[qs][1][0], sf[qs][1][1]), fmaxf(sf[qs][1][2], sf[qs][1][3])));
      pm = fmaxf(pm, fmaxf(fmaxf(fmaxf(sf[qs][2][0], sf[qs][2][1]), fmaxf(sf[qs][2][2], sf[qs][2][3])),
                           fmaxf(fmaxf(sf[qs][3][0], sf[qs][3][1]), fmaxf(sf[qs][3][2], sf[qs][3][3]))));
      pm = fmaxf(pm, __shfl_xor(pm, 16, 64));
      pm = fmaxf(pm, __shfl_xor(pm, 32, 64));
      if (__any(pm > m[qs] + 8.f)) {        // rescale path (rare after warmup)
        const float mo = m[qs];
        const float mn = fmaxf(mo, pm);
        m[qs] = mn;
        const float al = exp2f(mo - mn);
        l[qs] *= al;
#pragma unroll
        for (int d0 = 0; d0 < 8; ++d0) oacc[qs][d0] *= al;
      }
      const int qrow = qs * 16 + l16;
      float ps = 0.f;
#pragma unroll
      for (int kbb = 0; kbb < 4; ++kbb) {
        bf16x4 pw;
#pragma unroll
        for (int r = 0; r < 4; ++r) {
          float p = exp2f(sf[qs][kbb][r] - m[qs]);
          ps += p;
          pw[r] = f2bf_fast(p);
        }
        *reinterpret_cast<bf16x4*>(
            &Pw[qrow * 64 + (((2 * kbb + (lhi >> 1)) ^ (qrow & 7)) * 8) + ((lhi & 1) * 4)]) = pw;
      }
      ps += __shfl_xor(ps, 16, 64);
      ps += __shfl_xor(ps, 32, 64);
      l[qs] += ps;
    }

    // ---- PV: O^T = Vt * P^T; V-frag reused across both q-subtiles ----
    __builtin_amdgcn_s_setprio(1);
#pragma unroll
    for (int kc = 0; kc < 2; ++kc) {
      bf16x8 pb[2];
#pragma unroll
      for (int qs = 0; qs < 2; ++qs) {
        const int qrow = qs * 16 + l16;
        pb[qs] = *reinterpret_cast<const bf16x8*>(
            &Pw[qrow * 64 + (((4 * kc + lhi) ^ (qrow & 7)) * 8)]);
      }
#pragma unroll
      for (int d0 = 0; d0 < 8; ++d0) {
        const int vd = d0 * 16 + l16;
        bf16x8 av = *reinterpret_cast<const bf16x8*>(
            &Vlds[cur][vd * 64 + (((4 * kc + lhi) ^ (vd & 7)) * 8)]);
        oacc[0][d0] = __builtin_amdgcn_mfma_f32_16x16x32_bf16(av, pb[0], oacc[0][d0], 0, 0, 0);
        oacc[1][d0] = __builtin_amdgcn_mfma_f32_16x16x32_bf16(av, pb[1], oacc[1][d0], 0, 0, 0);
      }
    }
    __builtin_amdgcn_s_setprio(0);
    cur ^= 1;
  }

  // ---- epilogue ----
#pragma unroll
  for (int qs = 0; qs < 2; ++qs) {
    const float inv = 1.0f / l[qs];
    float* ob = out + ((size_t)bh * S_ + qrow0 + qs * 16 + l16) * D_;
#pragma unroll
    for (int d0 = 0; d0 < 8; ++d0) {
      float4 o4 = {oacc[qs][d0][0] * inv, oacc[qs][d0][1] * inv,
                   oacc[qs][d0][2] * inv, oacc[qs][d0][3] * inv};
      *reinterpret_cast<float4*>(ob + d0 * 16 + lhi * 4) = o4;
    }
  }
}

// ================= fallback (R1 kernel) if ws too small =================
__global__ __launch_bounds__(256, 4) void attn_fwd_v1(
    const float* __restrict__ q, const float* __restrict__ k,
    const float* __restrict__ v, float* __restrict__ out)
{
  __shared__ __align__(16) short Klds[32 * 128];
  __shared__ __align__(16) short Vlds[128 * 40];
  __shared__ __align__(16) short Plds[4][16 * 40];
  const int lid = blockIdx.x;
  const int swz = (lid & 7) * 128 + (lid >> 3);
  const int qt = swz & 31;
  const int bh = swz >> 5;
  const int tid = threadIdx.x;
  const int wid = tid >> 6;
  const int lane = tid & 63;
  const int l16 = lane & 15;
  const int lhi = lane >> 4;
  const int qrow0 = qt * 64 + wid * 16;
  const float* qg = q + ((size_t)bh * S_ + qrow0 + l16) * D_;
  const float* kg = k + (size_t)bh * S_ * D_;
  const float* vg = v + (size_t)bh * S_ * D_;
  bf16x8 aq[4];
#pragma unroll
  for (int ks = 0; ks < 4; ++ks) {
    const float* p = qg + ks * 32 + lhi * 8;
    float4 f0 = *reinterpret_cast<const float4*>(p);
    float4 f1 = *reinterpret_cast<const float4*>(p + 4);
    bf16x8 a;
    a[0] = f2bf(f0.x * QSCALE); a[1] = f2bf(f0.y * QSCALE);
    a[2] = f2bf(f0.z * QSCALE); a[3] = f2bf(f0.w * QSCALE);
    a[4] = f2bf(f1.x * QSCALE); a[5] = f2bf(f1.y * QSCALE);
    a[6] = f2bf(f1.z * QSCALE); a[7] = f2bf(f1.w * QSCALE);
    aq[ks] = a;
  }
  float mrow[4], lrow[4];
  f32x4 oacc[8];
#pragma unroll
  for (int r = 0; r < 4; ++r) { mrow[r] = -1e30f; lrow[r] = 0.f; }
#pragma unroll
  for (int i = 0; i < 8; ++i) oacc[i] = (f32x4){0.f, 0.f, 0.f, 0.f};
  for (int t = 0; t < S_ / 32; ++t) {
    const int kv0 = t * 32;
    __syncthreads();
#pragma unroll
    for (int i = 0; i < 2; ++i) {
      const int g = tid * 2 + i;
      const int row = g >> 4;
      const int c8 = g & 15;
      const float* ksrc = kg + (size_t)(kv0 + row) * D_ + c8 * 8;
      float4 f0 = *reinterpret_cast<const float4*>(ksrc);
      float4 f1 = *reinterpret_cast<const float4*>(ksrc + 4);
      bf16x8 kk;
      kk[0] = f2bf(f0.x); kk[1] = f2bf(f0.y); kk[2] = f2bf(f0.z); kk[3] = f2bf(f0.w);
      kk[4] = f2bf(f1.x); kk[5] = f2bf(f1.y); kk[6] = f2bf(f1.z); kk[7] = f2bf(f1.w);
      *reinterpret_cast<bf16x8*>(
          &Klds[row * D_ + ((c8 * 8) ^ ((row & 7) << 3))]) = kk;
      const float* vsrc = vg + (size_t)(kv0 + row) * D_ + c8 * 8;
      float4 g0 = *reinterpret_cast<const float4*>(vsrc);
      float4 g1 = *reinterpret_cast<const float4*>(vsrc + 4);
      const int dbase = c8 * 8;
      Vlds[(dbase + 0) * 40 + row] = f2bf(g0.x);
      Vlds[(dbase + 1) * 40 + row] = f2bf(g0.y);
      Vlds[(dbase + 2) * 40 + row] = f2bf(g0.z);
      Vlds[(dbase + 3) * 40 + row] = f2bf(g0.w);
      Vlds[(dbase + 4) * 40 + row] = f2bf(g1.x);
      Vlds[(dbase + 5) * 40 + row] = f2bf(g1.y);
      Vlds[(dbase + 6) * 40 + row] = f2bf(g1.z);
      Vlds[(dbase + 7) * 40 + row] = f2bf(g1.w);
    }
    __syncthreads();
    f32x4 sfrag[2];
#pragma unroll
    for (int kb = 0; kb < 2; ++kb) {
      f32x4 acc = (f32x4){0.f, 0.f, 0.f, 0.f};
#pragma unroll
      for (int ks = 0; ks < 4; ++ks) {
        const int rowk = kb * 16 + l16;
        bf16x8 bk = *reinterpret_cast<const bf16x8*>(
            &Klds[rowk * D_ + (((ks * 4 + lhi) * 8) ^ ((rowk & 7) << 3))]);
        acc = __builtin_amdgcn_mfma_f32_16x16x32_bf16(aq[ks], bk, acc, 0, 0, 0);
      }
      sfrag[kb] = acc;
    }
    float mt[4];
#pragma unroll
    for (int r = 0; r < 4; ++r) mt[r] = fmaxf(sfrag[0][r], sfrag[1][r]);
#pragma unroll
    for (int off = 1; off < 16; off <<= 1)
#pragma unroll
      for (int r = 0; r < 4; ++r) mt[r] = fmaxf(mt[r], __shfl_xor(mt[r], off, 64));
    float al[4], ps[4];
#pragma unroll
    for (int r = 0; r < 4; ++r) {
      float mn = fmaxf(mrow[r], mt[r]);
      al[r] = exp2f(mrow[r] - mn);
      mrow[r] = mn;
      ps[r] = 0.f;
    }
#pragma unroll
    for (int kb = 0; kb < 2; ++kb)
#pragma unroll
      for (int r = 0; r < 4; ++r) {
        float p = exp2f(sfrag[kb][r] - mrow[r]);
        ps[r] += p;
        Plds[wid][(lhi * 4 + r) * 40 + kb * 16 + l16] = f2bf(p);
      }
#pragma unroll
    for (int off = 1; off < 16; off <<= 1)
#pragma unroll
      for (int r = 0; r < 4; ++r) ps[r] += __shfl_xor(ps[r], off, 64);
#pragma unroll
    for (int r = 0; r < 4; ++r) lrow[r] = lrow[r] * al[r] + ps[r];
#pragma unroll
    for (int i = 0; i < 8; ++i)
#pragma unroll
      for (int r = 0; r < 4; ++r) oacc[i][r] *= al[r];
    bf16x8 ap = *reinterpret_cast<const bf16x8*>(&Plds[wid][l16 * 40 + lhi * 8]);
#pragma unroll
    for (int d0 = 0; d0 < 8; ++d0) {
      bf16x8 bv = *reinterpret_cast<const bf16x8*>(
          &Vlds[(d0 * 16 + l16) * 40 + lhi * 8]);
      oacc[d0] = __builtin_amdgcn_mfma_f32_16x16x32_bf16(ap, bv, oacc[d0], 0, 0, 0);
    }
  }
#pragma unroll
  for (int r = 0; r < 4; ++r) {
    float inv = 1.0f / lrow[r];
    float* orow = out + ((size_t)bh * S_ + qrow0 + lhi * 4 + r) * D_ + l16;
#pragma unroll
    for (int d0 = 0; d0 < 8; ++d0) orow[d0 * 16] = oacc[d0][r] * inv;
  }
}

extern "C" void kernel_launch(void* const* d_in, const int* in_sizes, int n_in,
                              void* d_out, int out_size, void* d_ws, size_t ws_size,
                              hipStream_t stream) {
  (void)in_sizes; (void)n_in; (void)out_size;
  const float* q = (const float*)d_in[0];
  const float* k = (const float*)d_in[1];
  const float* v = (const float*)d_in[2];
  float* o = (float*)d_out;
  const size_t NEL = (size_t)BH * S_ * D_;
  const size_t need = NEL * 2 * sizeof(short);   // kb + vt, 33.6 MB
  if (ws_size >= need) {
    short* kb = (short*)d_ws;
    short* vt = kb + NEL;
    hipLaunchKernelGGL(prep_k, dim3(2048), dim3(256), 0, stream, k, kb);
    hipLaunchKernelGGL(prep_vt, dim3(1024), dim3(256), 0, stream, v, vt);
    hipLaunchKernelGGL(attn_fwd_v3, dim3(512), dim3(256), 0, stream, q, kb, vt, o);
  } else {
    hipLaunchKernelGGL(attn_fwd_v1, dim3(1024), dim3(256), 0, stream, q, k, v, o);
  }
}

// Round 4
// 126.160 us; speedup vs baseline: 2.8642x; 1.0160x over previous
//
#include <hip/hip_runtime.h>
#include <stdint.h>

typedef __attribute__((ext_vector_type(4))) float f32x4;
typedef __attribute__((ext_vector_type(16))) float f32x16;
typedef __attribute__((ext_vector_type(8))) short bf16x8;

constexpr int S_ = 2048;
constexpr int D_ = 128;
constexpr int BH = 32;
constexpr int KB = 64;
constexpr int NT = S_ / KB;
// fold 1/sqrt(128) * log2(e) into Q so scores are in log2 domain
constexpr float QSCALE = 0.08838834764831845f * 1.4426950408889634f;

__device__ __forceinline__ short f2bf(float f) {
  uint32_t u = __float_as_uint(f);
  u += 0x7fffu + ((u >> 16) & 1u);
  return (short)(u >> 16);
}

__device__ __forceinline__ void gll16(const void* g, void* l) {
  __builtin_amdgcn_global_load_lds(
      (const __attribute__((address_space(1))) void*)g,
      (__attribute__((address_space(3))) void*)l, 16, 0, 0);
}

// ================= prep 1: k -> bf16 =================
__global__ void prep_k(const float* __restrict__ k, short* __restrict__ kb) {
  const size_t N8 = (size_t)BH * S_ * D_ / 8;
  size_t i = (size_t)blockIdx.x * blockDim.x + threadIdx.x;
  const size_t stride = (size_t)gridDim.x * blockDim.x;
  for (; i < N8; i += stride) {
    float4 a = reinterpret_cast<const float4*>(k)[i * 2];
    float4 b = reinterpret_cast<const float4*>(k)[i * 2 + 1];
    bf16x8 o;
    o[0] = f2bf(a.x); o[1] = f2bf(a.y); o[2] = f2bf(a.z); o[3] = f2bf(a.w);
    o[4] = f2bf(b.x); o[5] = f2bf(b.y); o[6] = f2bf(b.z); o[7] = f2bf(b.w);
    reinterpret_cast<bf16x8*>(kb)[i] = o;
  }
}

// ================= prep 2: v -> bf16 transposed per head: vt[bh][d][s] =================
__global__ void prep_vt(const float* __restrict__ v, short* __restrict__ vt) {
  __shared__ __align__(16) short Lt[64][136];
  const int bh = blockIdx.x >> 5;
  const int s0 = (blockIdx.x & 31) * 64;
  const int t = threadIdx.x;
#pragma unroll
  for (int i = 0; i < 4; ++i) {
    int g = t + 256 * i;
    int r = g >> 4, c8 = g & 15;
    const float* src = v + ((size_t)bh * S_ + s0 + r) * D_ + c8 * 8;
    float4 f0 = *reinterpret_cast<const float4*>(src);
    float4 f1 = *reinterpret_cast<const float4*>(src + 4);
    bf16x8 o;
    o[0] = f2bf(f0.x); o[1] = f2bf(f0.y); o[2] = f2bf(f0.z); o[3] = f2bf(f0.w);
    o[4] = f2bf(f1.x); o[5] = f2bf(f1.y); o[6] = f2bf(f1.z); o[7] = f2bf(f1.w);
    *reinterpret_cast<bf16x8*>(&Lt[r][c8 * 8]) = o;
  }
  __syncthreads();
#pragma unroll
  for (int i = 0; i < 4; ++i) {
    int g = t * 4 + i;
    int d = g >> 3, s8 = g & 7;
    bf16x8 o;
#pragma unroll
    for (int j = 0; j < 8; ++j) o[j] = Lt[s8 * 8 + j][d];
    *reinterpret_cast<bf16x8*>(&vt[((size_t)bh * D_ + d) * S_ + s0 + s8 * 8]) = o;
  }
}

// ===== main attention: 4 waves x 32 q (32x32 MFMA), KB=64, P in registers =====
// K LDS layout: [k16 granule 0..15][kv row 0..63][8 bf16]  (conflict-free b128 reads)
// V LDS layout: [kv granule 0..7][d row 0..127][8 bf16]
__global__ __launch_bounds__(256, 2) void attn_fwd_v4(
    const float* __restrict__ q, const short* __restrict__ kbf,
    const short* __restrict__ vt, float* __restrict__ out)
{
  __shared__ __align__(16) short Klds[2][64 * 128];
  __shared__ __align__(16) short Vlds[2][128 * 64];

  const int lid = blockIdx.x;
  const int swz = (lid & 7) * 64 + (lid >> 3);   // bijective: 512 % 8 == 0
  const int qt = swz & 15;
  const int bh = swz >> 4;

  const int tid = threadIdx.x;
  const int wid = tid >> 6;
  const int lane = tid & 63;
  const int l32 = lane & 31;
  const int hi = lane >> 5;

  const int qrow = qt * 128 + wid * 32 + l32;

  // ---- Q B-fragments: bq[s][j] = Q[qrow][s*16 + hi*8 + j], scaled ----
  bf16x8 bq[8];
  {
    const float* qg = q + ((size_t)bh * S_ + qrow) * D_ + hi * 8;
#pragma unroll
    for (int s = 0; s < 8; ++s) {
      float4 f0 = *reinterpret_cast<const float4*>(qg + s * 16);
      float4 f1 = *reinterpret_cast<const float4*>(qg + s * 16 + 4);
      bf16x8 a;
      a[0] = f2bf(f0.x * QSCALE); a[1] = f2bf(f0.y * QSCALE);
      a[2] = f2bf(f0.z * QSCALE); a[3] = f2bf(f0.w * QSCALE);
      a[4] = f2bf(f1.x * QSCALE); a[5] = f2bf(f1.y * QSCALE);
      a[6] = f2bf(f1.z * QSCALE); a[7] = f2bf(f1.w * QSCALE);
      bq[s] = a;
    }
  }

  const short* kg = kbf + (size_t)bh * S_ * D_;
  const short* vg = vt + (size_t)bh * D_ * S_;

  // staging: granule G = j*256 + wid*64 + lane; LDS dest linear (wave-uniform base)
  auto stage = [&](int buf, int kv0) {
#pragma unroll
    for (int j = 0; j < 4; ++j)
      gll16(kg + (size_t)kv0 * D_ + lane * D_ + (j * 4 + wid) * 8,
            &Klds[buf][(j * 256 + wid * 64) * 8]);
#pragma unroll
    for (int j = 0; j < 4; ++j)
      gll16(vg + kv0 + (size_t)((wid & 1) * 64 + lane) * S_ + (j * 2 + (wid >> 1)) * 8,
            &Vlds[buf][(j * 256 + wid * 64) * 8]);
  };

  float m = -1e30f, l = 0.f;
  f32x16 oacc[4];
#pragma unroll
  for (int d0 = 0; d0 < 4; ++d0)
#pragma unroll
    for (int r = 0; r < 16; ++r) oacc[d0][r] = 0.f;

  stage(0, 0);
  int cur = 0;
  for (int t = 0; t < NT; ++t) {
    __syncthreads();                       // tile t staged; joins waves
    if (t + 1 < NT) stage(cur ^ 1, (t + 1) * KB);

    const short* Kb = &Klds[cur][0];
    const short* Vb = &Vlds[cur][0];

    // ---- QK^T: S^T[kv][q] = K * Q^T, two 32-kv chunks ----
    f32x16 sf0, sf1;
#pragma unroll
    for (int r = 0; r < 16; ++r) { sf0[r] = 0.f; sf1[r] = 0.f; }
    __builtin_amdgcn_s_setprio(1);
#pragma unroll
    for (int s = 0; s < 8; ++s) {
      bf16x8 k0 = *reinterpret_cast<const bf16x8*>(
          &Kb[((s * 2 + hi) * 64 + l32) * 8]);
      bf16x8 k1 = *reinterpret_cast<const bf16x8*>(
          &Kb[((s * 2 + hi) * 64 + 32 + l32) * 8]);
      sf0 = __builtin_amdgcn_mfma_f32_32x32x16_bf16(k0, bq[s], sf0, 0, 0, 0);
      sf1 = __builtin_amdgcn_mfma_f32_32x32x16_bf16(k1, bq[s], sf1, 0, 0, 0);
    }
    __builtin_amdgcn_s_setprio(0);

    // ---- online softmax: lane owns q = lane&31; reduce over hi only ----
    float pm = fmaxf(sf0[0], sf0[1]);
#pragma unroll
    for (int r = 2; r < 16; ++r) pm = fmaxf(pm, sf0[r]);
#pragma unroll
    for (int r = 0; r < 16; ++r) pm = fmaxf(pm, sf1[r]);
    pm = fmaxf(pm, __shfl_xor(pm, 32, 64));
    if (__any(pm > m + 8.f)) {             // defer-max: rescale rarely
      const float mo = m;
      m = fmaxf(mo, pm);
      const float al = exp2f(mo - m);
      l *= al;
#pragma unroll
      for (int d0 = 0; d0 < 4; ++d0)
#pragma unroll
        for (int r = 0; r < 16; ++r) oacc[d0][r] *= al;
    }

    float ps = 0.f;
    // ---- per chunk: exp -> cvt_pk -> permlane32_swap -> PV MFMA ----
#define PROCESS_CHUNK(SF, C)                                                    \
    {                                                                           \
      uint32_t w[8];                                                            \
      _Pragma("unroll")                                                         \
      for (int i2 = 0; i2 < 8; ++i2) {                                          \
        float e0 = exp2f(SF[2 * i2] - m);                                       \
        float e1 = exp2f(SF[2 * i2 + 1] - m);                                   \
        ps += e0 + e1;                                                          \
        asm("v_cvt_pk_bf16_f32 %0, %1, %2" : "=v"(w[i2]) : "v"(e0), "v"(e1));   \
      }                                                                         \
      asm("v_permlane32_swap_b32 %0, %1" : "+v"(w[0]), "+v"(w[2]));             \
      asm("v_permlane32_swap_b32 %0, %1" : "+v"(w[1]), "+v"(w[3]));             \
      asm("v_permlane32_swap_b32 %0, %1" : "+v"(w[4]), "+v"(w[6]));             \
      asm("v_permlane32_swap_b32 %0, %1" : "+v"(w[5]), "+v"(w[7]));             \
      union { int4 i4; bf16x8 b; } u0, u1;                                      \
      u0.i4 = (int4){(int)w[0], (int)w[1], (int)w[2], (int)w[3]};               \
      u1.i4 = (int4){(int)w[4], (int)w[5], (int)w[6], (int)w[7]};               \
      __builtin_amdgcn_s_setprio(1);                                            \
      _Pragma("unroll")                                                         \
      for (int d0 = 0; d0 < 4; ++d0) {                                          \
        bf16x8 av = *reinterpret_cast<const bf16x8*>(                           \
            &Vb[(((C) * 4 + hi) * 128 + d0 * 32 + l32) * 8]);                   \
        oacc[d0] = __builtin_amdgcn_mfma_f32_32x32x16_bf16(av, u0.b, oacc[d0], 0, 0, 0); \
      }                                                                         \
      _Pragma("unroll")                                                         \
      for (int d0 = 0; d0 < 4; ++d0) {                                          \
        bf16x8 av = *reinterpret_cast<const bf16x8*>(                           \
            &Vb[(((C) * 4 + 2 + hi) * 128 + d0 * 32 + l32) * 8]);               \
        oacc[d0] = __builtin_amdgcn_mfma_f32_32x32x16_bf16(av, u1.b, oacc[d0], 0, 0, 0); \
      }                                                                         \
      __builtin_amdgcn_s_setprio(0);                                            \
    }

    PROCESS_CHUNK(sf0, 0)
    PROCESS_CHUNK(sf1, 1)
#undef PROCESS_CHUNK

    ps += __shfl_xor(ps, 32, 64);
    l += ps;
    cur ^= 1;
  }

  // ---- epilogue: O^T frag -> out[q][d] ----
  const float inv = 1.0f / l;
  float* ob = out + ((size_t)bh * S_ + qrow) * D_;
#pragma unroll
  for (int d0 = 0; d0 < 4; ++d0)
#pragma unroll
    for (int r2 = 0; r2 < 4; ++r2) {
      float4 o4 = {oacc[d0][r2 * 4 + 0] * inv, oacc[d0][r2 * 4 + 1] * inv,
                   oacc[d0][r2 * 4 + 2] * inv, oacc[d0][r2 * 4 + 3] * inv};
      *reinterpret_cast<float4*>(ob + d0 * 32 + r2 * 8 + hi * 4) = o4;
    }
}

// ================= fallback (R1 kernel) if ws too small =================
__global__ __launch_bounds__(256, 4) void attn_fwd_v1(
    const float* __restrict__ q, const float* __restrict__ k,
    const float* __restrict__ v, float* __restrict__ out)
{
  __shared__ __align__(16) short Klds[32 * 128];
  __shared__ __align__(16) short Vlds[128 * 40];
  __shared__ __align__(16) short Plds[4][16 * 40];
  const int lid = blockIdx.x;
  const int swz = (lid & 7) * 128 + (lid >> 3);
  const int qt = swz & 31;
  const int bh = swz >> 5;
  const int tid = threadIdx.x;
  const int wid = tid >> 6;
  const int lane = tid & 63;
  const int l16 = lane & 15;
  const int lhi = lane >> 4;
  const int qrow0 = qt * 64 + wid * 16;
  const float* qg = q + ((size_t)bh * S_ + qrow0 + l16) * D_;
  const float* kg = k + (size_t)bh * S_ * D_;
  const float* vg = v + (size_t)bh * S_ * D_;
  bf16x8 aq[4];
#pragma unroll
  for (int ks = 0; ks < 4; ++ks) {
    const float* p = qg + ks * 32 + lhi * 8;
    float4 f0 = *reinterpret_cast<const float4*>(p);
    float4 f1 = *reinterpret_cast<const float4*>(p + 4);
    bf16x8 a;
    a[0] = f2bf(f0.x * QSCALE); a[1] = f2bf(f0.y * QSCALE);
    a[2] = f2bf(f0.z * QSCALE); a[3] = f2bf(f0.w * QSCALE);
    a[4] = f2bf(f1.x * QSCALE); a[5] = f2bf(f1.y * QSCALE);
    a[6] = f2bf(f1.z * QSCALE); a[7] = f2bf(f1.w * QSCALE);
    aq[ks] = a;
  }
  float mrow[4], lrow[4];
  f32x4 oacc[8];
#pragma unroll
  for (int r = 0; r < 4; ++r) { mrow[r] = -1e30f; lrow[r] = 0.f; }
#pragma unroll
  for (int i = 0; i < 8; ++i) oacc[i] = (f32x4){0.f, 0.f, 0.f, 0.f};
  for (int t = 0; t < S_ / 32; ++t) {
    const int kv0 = t * 32;
    __syncthreads();
#pragma unroll
    for (int i = 0; i < 2; ++i) {
      const int g = tid * 2 + i;
      const int row = g >> 4;
      const int c8 = g & 15;
      const float* ksrc = kg + (size_t)(kv0 + row) * D_ + c8 * 8;
      float4 f0 = *reinterpret_cast<const float4*>(ksrc);
      float4 f1 = *reinterpret_cast<const float4*>(ksrc + 4);
      bf16x8 kk;
      kk[0] = f2bf(f0.x); kk[1] = f2bf(f0.y); kk[2] = f2bf(f0.z); kk[3] = f2bf(f0.w);
      kk[4] = f2bf(f1.x); kk[5] = f2bf(f1.y); kk[6] = f2bf(f1.z); kk[7] = f2bf(f1.w);
      *reinterpret_cast<bf16x8*>(
          &Klds[row * D_ + ((c8 * 8) ^ ((row & 7) << 3))]) = kk;
      const float* vsrc = vg + (size_t)(kv0 + row) * D_ + c8 * 8;
      float4 g0 = *reinterpret_cast<const float4*>(vsrc);
      float4 g1 = *reinterpret_cast<const float4*>(vsrc + 4);
      const int dbase = c8 * 8;
      Vlds[(dbase + 0) * 40 + row] = f2bf(g0.x);
      Vlds[(dbase + 1) * 40 + row] = f2bf(g0.y);
      Vlds[(dbase + 2) * 40 + row] = f2bf(g0.z);
      Vlds[(dbase + 3) * 40 + row] = f2bf(g0.w);
      Vlds[(dbase + 4) * 40 + row] = f2bf(g1.x);
      Vlds[(dbase + 5) * 40 + row] = f2bf(g1.y);
      Vlds[(dbase + 6) * 40 + row] = f2bf(g1.z);
      Vlds[(dbase + 7) * 40 + row] = f2bf(g1.w);
    }
    __syncthreads();
    f32x4 sfrag[2];
#pragma unroll
    for (int kb = 0; kb < 2; ++kb) {
      f32x4 acc = (f32x4){0.f, 0.f, 0.f, 0.f};
#pragma unroll
      for (int ks = 0; ks < 4; ++ks) {
        const int rowk = kb * 16 + l16;
        bf16x8 bk = *reinterpret_cast<const bf16x8*>(
            &Klds[rowk * D_ + (((ks * 4 + lhi) * 8) ^ ((rowk & 7) << 3))]);
        acc = __builtin_amdgcn_mfma_f32_16x16x32_bf16(aq[ks], bk, acc, 0, 0, 0);
      }
      sfrag[kb] = acc;
    }
    float mt[4];
#pragma unroll
    for (int r = 0; r < 4; ++r) mt[r] = fmaxf(sfrag[0][r], sfrag[1][r]);
#pragma unroll
    for (int off = 1; off < 16; off <<= 1)
#pragma unroll
      for (int r = 0; r < 4; ++r) mt[r] = fmaxf(mt[r], __shfl_xor(mt[r], off, 64));
    float al[4], ps[4];
#pragma unroll
    for (int r = 0; r < 4; ++r) {
      float mn = fmaxf(mrow[r], mt[r]);
      al[r] = exp2f(mrow[r] - mn);
      mrow[r] = mn;
      ps[r] = 0.f;
    }
#pragma unroll
    for (int kb = 0; kb < 2; ++kb)
#pragma unroll
      for (int r = 0; r < 4; ++r) {
        float p = exp2f(sfrag[kb][r] - mrow[r]);
        ps[r] += p;
        Plds[wid][(lhi * 4 + r) * 40 + kb * 16 + l16] = f2bf(p);
      }
#pragma unroll
    for (int off = 1; off < 16; off <<= 1)
#pragma unroll
      for (int r = 0; r < 4; ++r) ps[r] += __shfl_xor(ps[r], off, 64);
#pragma unroll
    for (int r = 0; r < 4; ++r) lrow[r] = lrow[r] * al[r] + ps[r];
#pragma unroll
    for (int i = 0; i < 8; ++i)
#pragma unroll
      for (int r = 0; r < 4; ++r) oacc[i][r] *= al[r];
    bf16x8 ap = *reinterpret_cast<const bf16x8*>(&Plds[wid][l16 * 40 + lhi * 8]);
#pragma unroll
    for (int d0 = 0; d0 < 8; ++d0) {
      bf16x8 bv = *reinterpret_cast<const bf16x8*>(
          &Vlds[(d0 * 16 + l16) * 40 + lhi * 8]);
      oacc[d0] = __builtin_amdgcn_mfma_f32_16x16x32_bf16(ap, bv, oacc[d0], 0, 0, 0);
    }
  }
#pragma unroll
  for (int r = 0; r < 4; ++r) {
    float inv = 1.0f / lrow[r];
    float* orow = out + ((size_t)bh * S_ + qrow0 + lhi * 4 + r) * D_ + l16;
#pragma unroll
    for (int d0 = 0; d0 < 8; ++d0) orow[d0 * 16] = oacc[d0][r] * inv;
  }
}

extern "C" void kernel_launch(void* const* d_in, const int* in_sizes, int n_in,
                              void* d_out, int out_size, void* d_ws, size_t ws_size,
                              hipStream_t stream) {
  (void)in_sizes; (void)n_in; (void)out_size;
  const float* q = (const float*)d_in[0];
  const float* k = (const float*)d_in[1];
  const float* v = (const float*)d_in[2];
  float* o = (float*)d_out;
  const size_t NEL = (size_t)BH * S_ * D_;
  const size_t need = NEL * 2 * sizeof(short);   // kb + vt, 33.6 MB
  if (ws_size >= need) {
    short* kb = (short*)d_ws;
    short* vt = kb + NEL;
    hipLaunchKernelGGL(prep_k, dim3(2048), dim3(256), 0, stream, k, kb);
    hipLaunchKernelGGL(prep_vt, dim3(1024), dim3(256), 0, stream, v, vt);
    hipLaunchKernelGGL(attn_fwd_v4, dim3(512), dim3(256), 0, stream, q, kb, vt, o);
  } else {
    hipLaunchKernelGGL(attn_fwd_v1, dim3(1024), dim3(256), 0, stream, q, k, v, o);
  }
}